// Round 3
// baseline (224.484 us; speedup 1.0000x reference)
//
#include <hip/hip_runtime.h>
#include <hip/hip_cooperative_groups.h>
#include <math.h>
#include <stdint.h>

namespace cg = cooperative_groups;

#define RB 256      // block size
#define BLKS 512    // cooperative grid: 2 blocks/CU on 256 CUs
#define JT 128      // j-tile (keys) per block in rank phase (n/JT = 64 tiles)
#define IPT 4       // i-keys per thread in rank phase (8 i-chunks of 1024)
#define GM 1024     // Gauss-transform grid points
#define CH 64       // gt source chunk (n/CH = 128 source splits)

#define SCALE 0.84932180028801904f   // 1/sqrt(2 ln2): exp(-d^2/2) = exp2(-(SCALE*d)^2)
#define SQRT2PI 2.5066282746310002f
#define KFP 0.46971863934f           // 1/(SCALE*sqrt(2pi)) : dPhiSum/dx = KFP*A
#define LN2 0.69314718056f

__device__ __forceinline__ uint64_t order_key(float f, int idx) {
  unsigned u = __float_as_uint(f);
  u = (u & 0x80000000u) ? ~u : (u | 0x80000000u);
  return ((uint64_t)u << 32) | (unsigned)idx;
}

__device__ __forceinline__ float e_of(const float* theta, const float* dur, int i) {
  return logf(dur[i] + 1e-32f) - theta[i];   // deterministic: identical everywhere
}

// grid geometry from the sorted endpoints (identical fp ops in every consumer)
__device__ __forceinline__ void grid_geom(const float2* xe, int n, float* x0, float* hx) {
  float a = xe[0].x - 7.0f;        // ~8 sigma margin in prescaled units
  float b = xe[n - 1].x + 7.0f;
  *x0 = a;
  *hx = (b - a) / (float)(GM - 1);
}

// ---------------------------------------------------------------------------
// One cooperative kernel, 4 phases separated by grid.sync():
//  A: counting-rank partials (block-local LDS j-tile, IPT i-keys/thread:
//     one ds_read_b128 feeds 2*IPT = 8 comparisons -> VALU-bound)
//  B: rank-sum -> scatter into interleaved (x, ev), th_s; zero gbuf/out
//     (zeroing done by blocks 32..47, disjoint from scatter blocks 0..31)
//  C: Gauss transform (A,B,F,D) on GM grid points, sources staged in LDS
//  D: per-element Hermite interpolation + loss reduction
// Rationale: per-dispatch overhead measured ~6 us; 3 boundaries removed.
// ---------------------------------------------------------------------------
__global__ __launch_bounds__(RB, 2) void fused_kernel(
    const float* __restrict__ theta, const float* __restrict__ dur,
    const int* __restrict__ ev, int* __restrict__ rank_part,
    float2* __restrict__ xe, float* __restrict__ th_s,
    float* __restrict__ gbuf, float* __restrict__ out, int n) {
  cg::grid_group grid = cg::this_grid();
  __shared__ uint64_t kt[JT];
  __shared__ float2 cst[CH];
  __shared__ float red[RB / 64];

  const int tid = threadIdx.x;
  const int bid = blockIdx.x;

  // ---------------- Phase A: rank partials ----------------
  {
    const int bx = bid & 7;               // i-chunk (8 chunks of RB*IPT=1024)
    const int by = bid >> 3;              // j-tile  (64 tiles of JT=128)
    const int i0 = bx * (RB * IPT) + tid;
    uint64_t ki[IPT];
    #pragma unroll
    for (int p = 0; p < IPT; ++p) {
      int ii = i0 + p * RB;
      ki[p] = order_key(e_of(theta, dur, ii), ii);
    }
    if (tid < JT) {
      int j = by * JT + tid;
      kt[tid] = order_key(e_of(theta, dur, j), j);
    }
    __syncthreads();
    int cnt[IPT] = {0, 0, 0, 0};
    const ulonglong2* kt2 = (const ulonglong2*)kt;
    #pragma unroll 8
    for (int jj = 0; jj < JT / 2; ++jj) {
      ulonglong2 q = kt2[jj];             // LDS broadcast, 2 keys per read
      #pragma unroll
      for (int p = 0; p < IPT; ++p) {
        cnt[p] += (q.x < ki[p]) ? 1 : 0;
        cnt[p] += (q.y < ki[p]) ? 1 : 0;
      }
    }
    #pragma unroll
    for (int p = 0; p < IPT; ++p)
      rank_part[by * n + i0 + p * RB] = cnt[p];
  }

  grid.sync();

  // ---------------- Phase B: rank-sum + scatter + zero ----------------
  {
    int k = bid * RB + tid;
    if (k < n) {                          // blocks 0..31
      int r = 0;
      #pragma unroll 16
      for (int jch = 0; jch < 64; ++jch) r += rank_part[jch * n + k];  // coalesced
      ((float*)&xe[r])[0] = SCALE * e_of(theta, dur, k);
      ((float*)&xe[k])[1] = (float)ev[r];
      th_s[k] = theta[r];
    }
    int k2 = k - n;                       // blocks 32..47 zero gbuf (parallel)
    if (k2 >= 0 && k2 < 4 * GM) gbuf[k2] = 0.0f;
    if (k == n) out[0] = 0.0f;
  }

  grid.sync();

  // ---------------- Phase C: Gauss transform ----------------
  {
    float x0, hx;
    grid_geom(xe, n, &x0, &hx);
    int m = (bid & 3) * RB + tid;         // 4 m-chunks cover GM=1024
    float xm = fmaf((float)m, hx, x0);
    int jb = (bid >> 2) * CH;             // 128 source chunks of 64
    if (tid < CH) cst[tid] = xe[jb + tid];
    __syncthreads();
    const float P2S = 0.39169197f;  // 0.47047*sqrt(ln2): t = 1/(1+p|d|/sqrt2)
    float a = 0.0f, b = 0.0f, f = 0.0f, d = 0.0f;
    #pragma unroll 8
    for (int jj = 0; jj < CH; ++jj) {
      float2 q = cst[jj];                 // LDS broadcast
      float dp = xm - q.x;
      float g = __builtin_amdgcn_exp2f(-(dp * dp));  // exp(-d^2/2)
      float evg = q.y * g;
      a += g;
      b += evg;
      d = fmaf(dp, evg, d);
      // A&S 7.1.25 erf (p=0.47047, |err|<=2.5e-5), reuses g
      float tt = __builtin_amdgcn_rcpf(fmaf(P2S, __builtin_fabsf(dp), 1.0f));
      float poly = tt * (0.3480242f + tt * (-0.0958798f + tt * 0.7478556f));
      f += __builtin_copysignf(fmaf(-poly, g, 1.0f), dp);   // sign*erf
    }
    atomicAdd(&gbuf[m], a);
    atomicAdd(&gbuf[GM + m], b);
    atomicAdd(&gbuf[2 * GM + m], 0.5f * (float)CH + 0.5f * f);  // Phi = .5+.5*s
    atomicAdd(&gbuf[3 * GM + m], d);
  }

  grid.sync();

  // ---------------- Phase D: Hermite interpolation + loss ----------------
  {
    float x0, hx;
    grid_geom(xe, n, &x0, &hx);
    const float* A = gbuf;
    const float* B = gbuf + GM;
    const float* F = gbuf + 2 * GM;
    const float* D = gbuf + 3 * GM;
    int i = bid * RB + tid;

    float term = 0.0f;
    if (i < n) {
      float2 q = xe[i];
      float u = (q.x - x0) * __builtin_amdgcn_rcpf(hx);
      int m = (int)u;
      m = min(max(m, 0), GM - 2);
      float t = u - (float)m;
      t = fminf(fmaxf(t, 0.0f), 1.0f);
      float t2 = t * t, t3 = t2 * t;
      float h00 = 2.0f * t3 - 3.0f * t2 + 1.0f;
      float h01 = 3.0f * t2 - 2.0f * t3;
      float h10 = t3 - 2.0f * t2 + t;
      float h11 = t3 - t2;
      float Fi = F[m] * h00 + F[m + 1] * h01 +
                 hx * KFP * (A[m] * h10 + A[m + 1] * h11);
      float Bi = B[m] * h00 + B[m + 1] * h01 -
                 2.0f * LN2 * hx * (D[m] * h10 + D[m + 1] * h11);
      const float fn = (float)n;
      float condE = fmaxf(Bi, 0.0f) * (1.0f / SQRT2PI) / fn + fn * 1e-32f;
      float surv = fmaxf(Fi, 0.25f) / fn;    // exact math gives Fi >= 0.5
      term = (__logf(condE) - __logf(surv) + th_s[i]) * q.y;
    }

    if (bid < n / RB) {                   // only blocks with live terms reduce
      #pragma unroll
      for (int off = 32; off > 0; off >>= 1) term += __shfl_down(term, off, 64);
      int wave = tid >> 6, lane = tid & 63;
      if (lane == 0) red[wave] = term;
      __syncthreads();
      if (tid == 0) {
        float s = 0.0f;
        #pragma unroll
        for (int w = 0; w < RB / 64; ++w) s += red[w];
        atomicAdd(out, -s / (float)n);
      }
    }
  }
}

extern "C" void kernel_launch(void* const* d_in, const int* in_sizes, int n_in,
                              void* d_out, int out_size, void* d_ws, size_t ws_size,
                              hipStream_t stream) {
  const float* theta = (const float*)d_in[0];   // log_h (n,1) fp32
  const float* dur   = (const float*)d_in[1];   // durations (n,) fp32
  const int*   ev    = (const int*)d_in[2];     // events (n,) int32
  float* out = (float*)d_out;
  int n = in_sizes[1];

  // workspace layout (8-byte aligned first)
  char* ws = (char*)d_ws;
  float2* xe        = (float2*)ws;  ws += n * sizeof(float2);
  int*    rank_part = (int*)ws;     ws += (n / JT) * n * sizeof(int);
  float*  th_s      = (float*)ws;   ws += n * sizeof(float);
  float*  gbuf      = (float*)ws;   ws += 4 * GM * sizeof(float);  // A|B|F|D

  void* args[] = {(void*)&theta, (void*)&dur, (void*)&ev, (void*)&rank_part,
                  (void*)&xe, (void*)&th_s, (void*)&gbuf, (void*)&out, (void*)&n};
  hipLaunchCooperativeKernel((const void*)fused_kernel, dim3(BLKS), dim3(RB),
                             args, 0, stream);
}

// Round 4
// 206.466 us; speedup vs baseline: 1.0873x; 1.0873x over previous
//
#include <hip/hip_runtime.h>
#include <math.h>
#include <stdint.h>

#define RB 256      // block size
#define BLKS 512    // persistent grid: 2 blocks/CU on 256 CUs (capacity >= 8/CU)
#define JT 128      // j-tile (keys) per block in rank phase (n/JT = 64 tiles)
#define IPT 4       // i-keys per thread in rank phase (8 i-chunks of 1024)
#define GM 1024     // Gauss-transform grid points
#define CH 64       // gt source chunk (n/CH = 128 source splits)

#define SCALE 0.84932180028801904f   // 1/sqrt(2 ln2): exp(-d^2/2) = exp2(-(SCALE*d)^2)
#define SQRT2PI 2.5066282746310002f
#define KFP 0.46971863934f           // 1/(SCALE*sqrt(2pi)) : dPhiSum/dx = KFP*A
#define LN2 0.69314718056f

#define MAGIC 0x5F3759DFu            // canary: not a repeated-byte poison pattern

struct GBar { unsigned canary, cnt, gen, pad[29]; };   // one 128B line

// Sense-reversing grid barrier. Only tid 0 arrives; relaxed agent-scope spin
// (atomic loads go to the coherent point, no per-poll L2 invalidate); one
// release fence (wbL2) before arrival, one acquire fence (inv) after exit.
// cnt self-restores to 0 each use; gen grows monotonically across launches.
__device__ __forceinline__ void grid_bar(GBar* b, unsigned nb) {
  __syncthreads();
  if (threadIdx.x == 0) {
    __threadfence();                       // release: make phase writes visible
    unsigned g = __hip_atomic_load(&b->gen, __ATOMIC_RELAXED,
                                   __HIP_MEMORY_SCOPE_AGENT);
    unsigned old = __hip_atomic_fetch_add(&b->cnt, 1u, __ATOMIC_RELAXED,
                                          __HIP_MEMORY_SCOPE_AGENT);
    if (old == nb - 1u) {
      __hip_atomic_fetch_add(&b->cnt, (unsigned)(-(int)nb), __ATOMIC_RELAXED,
                             __HIP_MEMORY_SCOPE_AGENT);
      __hip_atomic_fetch_add(&b->gen, 1u, __ATOMIC_RELAXED,
                             __HIP_MEMORY_SCOPE_AGENT);
    } else {
      while (__hip_atomic_load(&b->gen, __ATOMIC_RELAXED,
                               __HIP_MEMORY_SCOPE_AGENT) == g)
        __builtin_amdgcn_s_sleep(8);
    }
    __threadfence();                       // acquire: invalidate stale lines
  }
  __syncthreads();
}

__device__ __forceinline__ uint64_t order_key(float f, int idx) {
  unsigned u = __float_as_uint(f);
  u = (u & 0x80000000u) ? ~u : (u | 0x80000000u);
  return ((uint64_t)u << 32) | (unsigned)idx;
}

__device__ __forceinline__ float e_of(const float* theta, const float* dur, int i) {
  return logf(dur[i] + 1e-32f) - theta[i];   // deterministic: identical everywhere
}

// grid geometry from the sorted endpoints (identical fp ops in every consumer)
__device__ __forceinline__ void grid_geom(const float2* xe, int n, float* x0, float* hx) {
  float a = xe[0].x - 7.0f;        // ~8 sigma margin in prescaled units
  float b = xe[n - 1].x + 7.0f;
  *x0 = a;
  *hx = (b - a) / (float)(GM - 1);
}

// ---------------------------------------------------------------------------
// One persistent kernel, 4 phases separated by hand-rolled grid barriers
// (cg::grid.sync measured ~48 us/sync on gfx950 -- unusable).
//  A: counting-rank partials (LDS j-tile, IPT=4 i-keys/thread)
//  B: rank-sum -> scatter (blocks 0..31); zero gbuf (blocks 32..47) + out
//  C: Gauss transform (A,B,F,D) on GM grid points, sources staged in LDS
//  D: per-element Hermite interpolation + loss reduction (blocks 0..31)
// ---------------------------------------------------------------------------
__global__ __launch_bounds__(RB, 2) void fused_kernel(
    const float* __restrict__ theta, const float* __restrict__ dur,
    const int* __restrict__ ev, int* __restrict__ rank_part,
    float2* __restrict__ xe, float* __restrict__ th_s,
    float* __restrict__ gbuf, GBar* __restrict__ bar,
    float* __restrict__ out, int n) {
  __shared__ uint64_t kt[JT];
  __shared__ float2 cst[CH];
  __shared__ float red[RB / 64];

  const int tid = threadIdx.x;
  const int bid = blockIdx.x;

  // Barrier init: workspace is poisoned between iterations; block 0 detects a
  // missing canary, re-inits {cnt,gen}, publishes canary with release. All
  // blocks gate on the canary before their first barrier arrival.
  if (bid == 0 && tid == 0) {
    if (__hip_atomic_load(&bar->canary, __ATOMIC_RELAXED,
                          __HIP_MEMORY_SCOPE_AGENT) != MAGIC) {
      __hip_atomic_store(&bar->cnt, 0u, __ATOMIC_RELAXED, __HIP_MEMORY_SCOPE_AGENT);
      __hip_atomic_store(&bar->gen, 0u, __ATOMIC_RELAXED, __HIP_MEMORY_SCOPE_AGENT);
      __threadfence();
      __hip_atomic_store(&bar->canary, MAGIC, __ATOMIC_RELAXED,
                         __HIP_MEMORY_SCOPE_AGENT);
    }
  }

  // ---------------- Phase A: rank partials ----------------
  {
    const int bx = bid & 7;               // i-chunk (8 chunks of RB*IPT=1024)
    const int by = bid >> 3;              // j-tile  (64 tiles of JT=128)
    const int i0 = bx * (RB * IPT) + tid;
    uint64_t ki[IPT];
    #pragma unroll
    for (int p = 0; p < IPT; ++p) {
      int ii = i0 + p * RB;
      ki[p] = order_key(e_of(theta, dur, ii), ii);
    }
    if (tid < JT) {
      int j = by * JT + tid;
      kt[tid] = order_key(e_of(theta, dur, j), j);
    }
    __syncthreads();
    int cnt[IPT] = {0, 0, 0, 0};
    const ulonglong2* kt2 = (const ulonglong2*)kt;
    #pragma unroll 8
    for (int jj = 0; jj < JT / 2; ++jj) {
      ulonglong2 q = kt2[jj];             // LDS broadcast, 2 keys per read
      #pragma unroll
      for (int p = 0; p < IPT; ++p) {
        cnt[p] += (q.x < ki[p]) ? 1 : 0;
        cnt[p] += (q.y < ki[p]) ? 1 : 0;
      }
    }
    #pragma unroll
    for (int p = 0; p < IPT; ++p)
      rank_part[by * n + i0 + p * RB] = cnt[p];
  }

  // gate on canary (cheap; almost always already set), then barrier
  if (tid == 0) {
    while (__hip_atomic_load(&bar->canary, __ATOMIC_RELAXED,
                             __HIP_MEMORY_SCOPE_AGENT) != MAGIC)
      __builtin_amdgcn_s_sleep(8);
  }
  grid_bar(bar, BLKS);

  // ---------------- Phase B: rank-sum + scatter + zero ----------------
  {
    int k = bid * RB + tid;
    if (k < n) {                          // blocks 0..31
      int r = 0;
      #pragma unroll 16
      for (int jch = 0; jch < 64; ++jch) r += rank_part[jch * n + k];  // coalesced
      ((float*)&xe[r])[0] = SCALE * e_of(theta, dur, k);
      ((float*)&xe[k])[1] = (float)ev[r];
      th_s[k] = theta[r];
    }
    int k2 = k - n;                       // blocks 32..47 zero gbuf (parallel)
    if (k2 >= 0 && k2 < 4 * GM) gbuf[k2] = 0.0f;
    if (k == n) out[0] = 0.0f;
  }

  grid_bar(bar, BLKS);

  // ---------------- Phase C: Gauss transform ----------------
  {
    float x0, hx;
    grid_geom(xe, n, &x0, &hx);
    int m = (bid & 3) * RB + tid;         // 4 m-chunks cover GM=1024
    float xm = fmaf((float)m, hx, x0);
    int jb = (bid >> 2) * CH;             // 128 source chunks of 64
    if (tid < CH) cst[tid] = xe[jb + tid];
    __syncthreads();
    const float P2S = 0.39169197f;  // 0.47047*sqrt(ln2): t = 1/(1+p|d|/sqrt2)
    float a = 0.0f, b = 0.0f, f = 0.0f, d = 0.0f;
    #pragma unroll 8
    for (int jj = 0; jj < CH; ++jj) {
      float2 q = cst[jj];                 // LDS broadcast
      float dp = xm - q.x;
      float g = __builtin_amdgcn_exp2f(-(dp * dp));  // exp(-d^2/2)
      float evg = q.y * g;
      a += g;
      b += evg;
      d = fmaf(dp, evg, d);
      // A&S 7.1.25 erf (p=0.47047, |err|<=2.5e-5), reuses g
      float tt = __builtin_amdgcn_rcpf(fmaf(P2S, __builtin_fabsf(dp), 1.0f));
      float poly = tt * (0.3480242f + tt * (-0.0958798f + tt * 0.7478556f));
      f += __builtin_copysignf(fmaf(-poly, g, 1.0f), dp);   // sign*erf
    }
    atomicAdd(&gbuf[m], a);
    atomicAdd(&gbuf[GM + m], b);
    atomicAdd(&gbuf[2 * GM + m], 0.5f * (float)CH + 0.5f * f);  // Phi = .5+.5*s
    atomicAdd(&gbuf[3 * GM + m], d);
  }

  grid_bar(bar, BLKS);

  // ---------------- Phase D: Hermite interpolation + loss ----------------
  {
    float x0, hx;
    grid_geom(xe, n, &x0, &hx);
    const float* A = gbuf;
    const float* B = gbuf + GM;
    const float* F = gbuf + 2 * GM;
    const float* D = gbuf + 3 * GM;
    int i = bid * RB + tid;

    float term = 0.0f;
    if (i < n) {
      float2 q = xe[i];
      float u = (q.x - x0) * __builtin_amdgcn_rcpf(hx);
      int m = (int)u;
      m = min(max(m, 0), GM - 2);
      float t = u - (float)m;
      t = fminf(fmaxf(t, 0.0f), 1.0f);
      float t2 = t * t, t3 = t2 * t;
      float h00 = 2.0f * t3 - 3.0f * t2 + 1.0f;
      float h01 = 3.0f * t2 - 2.0f * t3;
      float h10 = t3 - 2.0f * t2 + t;
      float h11 = t3 - t2;
      float Fi = F[m] * h00 + F[m + 1] * h01 +
                 hx * KFP * (A[m] * h10 + A[m + 1] * h11);
      float Bi = B[m] * h00 + B[m + 1] * h01 -
                 2.0f * LN2 * hx * (D[m] * h10 + D[m + 1] * h11);
      const float fn = (float)n;
      float condE = fmaxf(Bi, 0.0f) * (1.0f / SQRT2PI) / fn + fn * 1e-32f;
      float surv = fmaxf(Fi, 0.25f) / fn;    // exact math gives Fi >= 0.5
      term = (__logf(condE) - __logf(surv) + th_s[i]) * q.y;
    }

    if (bid < n / RB) {                   // only blocks with live terms reduce
      #pragma unroll
      for (int off = 32; off > 0; off >>= 1) term += __shfl_down(term, off, 64);
      int wave = tid >> 6, lane = tid & 63;
      if (lane == 0) red[wave] = term;
      __syncthreads();
      if (tid == 0) {
        float s = 0.0f;
        #pragma unroll
        for (int w = 0; w < RB / 64; ++w) s += red[w];
        atomicAdd(out, -s / (float)n);
      }
    }
  }
}

extern "C" void kernel_launch(void* const* d_in, const int* in_sizes, int n_in,
                              void* d_out, int out_size, void* d_ws, size_t ws_size,
                              hipStream_t stream) {
  const float* theta = (const float*)d_in[0];   // log_h (n,1) fp32
  const float* dur   = (const float*)d_in[1];   // durations (n,) fp32
  const int*   ev    = (const int*)d_in[2];     // events (n,) int32
  float* out = (float*)d_out;
  int n = in_sizes[1];

  // workspace layout (128B-aligned barrier line first)
  char* ws = (char*)d_ws;
  GBar*   bar       = (GBar*)ws;    ws += sizeof(GBar);
  float2* xe        = (float2*)ws;  ws += n * sizeof(float2);
  int*    rank_part = (int*)ws;     ws += (n / JT) * n * sizeof(int);
  float*  th_s      = (float*)ws;   ws += n * sizeof(float);
  float*  gbuf      = (float*)ws;   ws += 4 * GM * sizeof(float);  // A|B|F|D

  fused_kernel<<<BLKS, RB, 0, stream>>>(theta, dur, ev, rank_part,
                                        xe, th_s, gbuf, bar, out, n);
}

// Round 5
// 105.900 us; speedup vs baseline: 2.1198x; 1.9496x over previous
//
#include <hip/hip_runtime.h>
#include <math.h>
#include <stdint.h>

#define RB 256      // block size
#define KB 256      // rank blocks (n / IK)
#define IK 32       // i-keys owned per rank block
#define JS 32       // j-iterations per thread in rank phase (n / RB)
#define GB 512      // gt blocks
#define GM 1024     // Gauss-transform grid points
#define CH 64       // gt source chunk (n/CH = 128 source splits)

#define SCALE 0.84932180028801904f   // 1/sqrt(2 ln2): exp(-d^2/2) = exp2(-(SCALE*d)^2)
#define SQRT2PI 2.5066282746310002f
#define KFP 0.46971863934f           // 1/(SCALE*sqrt(2pi)) : dPhiSum/dx = KFP*A
#define LN2 0.69314718056f

__device__ __forceinline__ uint64_t order_key(float f, int idx) {
  unsigned u = __float_as_uint(f);
  u = (u & 0x80000000u) ? ~u : (u | 0x80000000u);
  return ((uint64_t)u << 32) | (unsigned)idx;
}

__device__ __forceinline__ float e_of(const float* theta, const float* dur, int i) {
  return logf(dur[i] + 1e-32f) - theta[i];   // deterministic: identical everywhere
}

// grid geometry from the sorted endpoints (identical fp ops in every consumer)
__device__ __forceinline__ void grid_geom(const float2* xe, int n, float* x0, float* hx) {
  float a = xe[0].x - 7.0f;        // ~8 sigma margin in prescaled units
  float b = xe[n - 1].x + 7.0f;
  *x0 = a;
  *hx = (b - a) / (float)(GM - 1);
}

// ---------------------------------------------------------------------------
// Kernel 1: full rank + scatter in ONE dispatch (no rank_part round-trip, no
// cross-block dependency). Block b owns i-keys [32b, 32b+32): staged via LDS,
// then held in registers by every thread (64 VGPR). Each thread streams a
// 32-element j-stripe (coalesced theta/dur + inline key) and compares against
// all 32 i-keys in registers. Wave shfl-reduce + LDS cross-wave sum yields the
// COMPLETE rank of each owned key; threads 0..31 scatter immediately:
//   xe[r].x = SCALE*e(k); xe[k].y = ev[r]; th_s[k] = theta[r]
// Side duties: blocks 0..15 zero gbuf; block 16 zeroes the done-counter.
// ---------------------------------------------------------------------------
__global__ __launch_bounds__(RB) void rank_scatter_kernel(
    const float* __restrict__ theta, const float* __restrict__ dur,
    const int* __restrict__ ev, float2* __restrict__ xe,
    float* __restrict__ th_s, float* __restrict__ gbuf,
    unsigned* __restrict__ done, int n) {
  __shared__ uint64_t kt[IK];
  __shared__ int part[4 * IK];
  const int tid = threadIdx.x, bid = blockIdx.x;
  const int k0 = bid * IK;

  if (tid < IK) kt[tid] = order_key(e_of(theta, dur, k0 + tid), k0 + tid);
  if (bid < 16) gbuf[bid * RB + tid] = 0.0f;        // 16*256 = 4*GM
  if (bid == 16 && tid == 0) *done = 0u;
  __syncthreads();

  uint64_t ki[IK];
  int cnt[IK];
  #pragma unroll
  for (int p = 0; p < IK; ++p) { ki[p] = kt[p]; cnt[p] = 0; }

  #pragma unroll 4
  for (int s = 0; s < JS; ++s) {
    int j = s * RB + tid;                            // coalesced stripe
    uint64_t jk = order_key(e_of(theta, dur, j), j);
    #pragma unroll
    for (int p = 0; p < IK; ++p) cnt[p] += (jk < ki[p]) ? 1 : 0;
  }

  // reduce each of the 32 counts across the 64-lane wave, then across waves
  #pragma unroll
  for (int p = 0; p < IK; ++p) {
    #pragma unroll
    for (int off = 32; off > 0; off >>= 1) cnt[p] += __shfl_down(cnt[p], off, 64);
  }
  int wave = tid >> 6, lane = tid & 63;
  if (lane == 0) {
    #pragma unroll
    for (int p = 0; p < IK; ++p) part[wave * IK + p] = cnt[p];
  }
  __syncthreads();

  if (tid < IK) {
    int r = part[tid] + part[IK + tid] + part[2 * IK + tid] + part[3 * IK + tid];
    int k = k0 + tid;
    ((float*)&xe[r])[0] = SCALE * e_of(theta, dur, k);   // scatter (distinct dword)
    ((float*)&xe[k])[1] = (float)ev[r];                  // inverse-perm side reorder
    th_s[k] = theta[r];
  }
}

// ---------------------------------------------------------------------------
// Kernel 2: Gauss transform + last-block final phase (no grid barrier; grid
// sync measured ~50 us/rendezvous on gfx950 in BOTH cg and hand-rolled forms).
// gt: dp = x_m - x_j (prescaled), accumulating per grid point m:
//   A = sum g; B = sum ev*g; F = sum Phi(d); D = sum dp*ev*g
// Each block then: syncthreads -> tid0 {release fence; ticket=fetch_add(done)}.
// The single block with ticket==GB-1 acquires and computes the entire Hermite
// interpolation + loss (8192 elems / 256 threads), storing out[0] directly.
// ---------------------------------------------------------------------------
__global__ __launch_bounds__(RB) void gt_final_kernel(
    const float2* __restrict__ xe, const float* __restrict__ th_s,
    float* __restrict__ gbuf, unsigned* __restrict__ done,
    float* __restrict__ out, int n) {
  __shared__ float2 cst[CH];
  __shared__ float red[RB / 64];
  __shared__ unsigned tick;
  const int tid = threadIdx.x, bid = blockIdx.x;

  float x0, hx;
  grid_geom(xe, n, &x0, &hx);

  // ---- gt phase ----
  {
    int m = (bid & 3) * RB + tid;         // 4 m-chunks cover GM=1024
    float xm = fmaf((float)m, hx, x0);
    int jb = (bid >> 2) * CH;             // 128 source chunks of 64
    if (tid < CH) cst[tid] = xe[jb + tid];
    __syncthreads();
    const float P2S = 0.39169197f;  // 0.47047*sqrt(ln2): t = 1/(1+p|d|/sqrt2)
    float a = 0.0f, b = 0.0f, f = 0.0f, d = 0.0f;
    #pragma unroll 8
    for (int jj = 0; jj < CH; ++jj) {
      float2 q = cst[jj];                 // LDS broadcast
      float dp = xm - q.x;
      float g = __builtin_amdgcn_exp2f(-(dp * dp));  // exp(-d^2/2)
      float evg = q.y * g;
      a += g;
      b += evg;
      d = fmaf(dp, evg, d);
      // A&S 7.1.25 erf (p=0.47047, |err|<=2.5e-5), reuses g
      float tt = __builtin_amdgcn_rcpf(fmaf(P2S, __builtin_fabsf(dp), 1.0f));
      float poly = tt * (0.3480242f + tt * (-0.0958798f + tt * 0.7478556f));
      f += __builtin_copysignf(fmaf(-poly, g, 1.0f), dp);   // sign*erf
    }
    atomicAdd(&gbuf[m], a);
    atomicAdd(&gbuf[GM + m], b);
    atomicAdd(&gbuf[2 * GM + m], 0.5f * (float)CH + 0.5f * f);  // Phi = .5+.5*s
    atomicAdd(&gbuf[3 * GM + m], d);
  }

  // ---- last-block handoff ----
  __syncthreads();                         // drains this block's atomics (vmcnt)
  if (tid == 0) {
    __threadfence();                       // release: atomics visible device-wide
    tick = __hip_atomic_fetch_add(done, 1u, __ATOMIC_ACQ_REL,
                                  __HIP_MEMORY_SCOPE_AGENT);
  }
  __syncthreads();
  if (tick != GB - 1) return;              // all but one block exit (no spinning)

  // ---- final phase (single block; all 511 others' atomics are complete) ----
  __threadfence();                         // acquire: invalidate stale lines
  const float* A = gbuf;
  const float* B = gbuf + GM;
  const float* F = gbuf + 2 * GM;
  const float* D = gbuf + 3 * GM;

  float acc = 0.0f;
  for (int i = tid; i < n; i += RB) {
    float2 q = xe[i];
    float u = (q.x - x0) * __builtin_amdgcn_rcpf(hx);
    int m = (int)u;
    m = min(max(m, 0), GM - 2);
    float t = u - (float)m;
    t = fminf(fmaxf(t, 0.0f), 1.0f);
    float t2 = t * t, t3 = t2 * t;
    float h00 = 2.0f * t3 - 3.0f * t2 + 1.0f;
    float h01 = 3.0f * t2 - 2.0f * t3;
    float h10 = t3 - 2.0f * t2 + t;
    float h11 = t3 - t2;
    float Fi = F[m] * h00 + F[m + 1] * h01 +
               hx * KFP * (A[m] * h10 + A[m + 1] * h11);
    float Bi = B[m] * h00 + B[m + 1] * h01 -
               2.0f * LN2 * hx * (D[m] * h10 + D[m + 1] * h11);
    const float fn = (float)n;
    float condE = fmaxf(Bi, 0.0f) * (1.0f / SQRT2PI) / fn + fn * 1e-32f;
    float surv = fmaxf(Fi, 0.25f) / fn;    // exact math gives Fi >= 0.5
    acc += (__logf(condE) - __logf(surv) + th_s[i]) * q.y;
  }

  #pragma unroll
  for (int off = 32; off > 0; off >>= 1) acc += __shfl_down(acc, off, 64);
  int wave = tid >> 6, lane = tid & 63;
  if (lane == 0) red[wave] = acc;
  __syncthreads();
  if (tid == 0) {
    float s = 0.0f;
    #pragma unroll
    for (int w = 0; w < RB / 64; ++w) s += red[w];
    out[0] = -s / (float)n;                // single writer: direct store
  }
}

extern "C" void kernel_launch(void* const* d_in, const int* in_sizes, int n_in,
                              void* d_out, int out_size, void* d_ws, size_t ws_size,
                              hipStream_t stream) {
  const float* theta = (const float*)d_in[0];   // log_h (n,1) fp32
  const float* dur   = (const float*)d_in[1];   // durations (n,) fp32
  const int*   ev    = (const int*)d_in[2];     // events (n,) int32
  float* out = (float*)d_out;
  int n = in_sizes[1];

  // workspace layout (8-byte aligned first)
  char* ws = (char*)d_ws;
  float2*   xe   = (float2*)ws;    ws += n * sizeof(float2);
  float*    th_s = (float*)ws;     ws += n * sizeof(float);
  float*    gbuf = (float*)ws;     ws += 4 * GM * sizeof(float);  // A|B|F|D
  unsigned* done = (unsigned*)ws;  ws += sizeof(unsigned);

  rank_scatter_kernel<<<KB, RB, 0, stream>>>(theta, dur, ev, xe, th_s,
                                             gbuf, done, n);
  gt_final_kernel<<<GB, RB, 0, stream>>>(xe, th_s, gbuf, done, out, n);
}